// Round 2
// baseline (1017.015 us; speedup 1.0000x reference)
//
#include <hip/hip_runtime.h>
#include <hip/hip_bf16.h>

#define B_ 4
#define H_ 240
#define W_ 1216
#define HW_ (H_*W_)        /* 291840 */
#define N1_ (B_*HW_)       /* 1167360 */
#define PT_ 18

// ---------- dtype-agnostic load/store (runtime bf16-vs-fp32 probe) ----------
// aff_scale_const == 4.0: bf16 -> halfword 0x4080 at offset 0; fp32 -> 0x0000.
__device__ __forceinline__ bool probe_bf16(const void* scale_ptr) {
    return ((const unsigned short*)scale_ptr)[0] == 0x4080;
}

__device__ __forceinline__ float ldin(const void* p, int i, bool bf) {
    if (bf) {
        unsigned int u = (unsigned int)((const unsigned short*)p)[i];
        return __uint_as_float(u << 16);
    }
    return ((const float*)p)[i];
}

__device__ __forceinline__ void stout(void* p, int i, bool bf, float v) {
    if (bf) ((__hip_bfloat16*)p)[i] = __float2bfloat16(v);
    else    ((float*)p)[i] = v;
}

// ---------------- kernel 1: stage conv weights to fp32 scratch --------------
__global__ __launch_bounds__(256) void k_prep_w(const void* __restrict__ w_oa,
                                                const void* __restrict__ b_oa,
                                                const void* __restrict__ scale,
                                                float* __restrict__ wc) {
    bool bf = probe_bf16(scale);
    int i = blockIdx.x * 256 + threadIdx.x;
    if (i < 1728) wc[i] = ldin(w_oa, i, bf);
    if (i < 24)   wc[1728 + i] = ldin(b_oa, i, bf);
}

// ---------------- kernel 2: feat0 = mask ? feat_fix : feat_init -------------
__global__ __launch_bounds__(256) void k_init(const void* __restrict__ finit,
                                              const void* __restrict__ ffix,
                                              const void* __restrict__ scale,
                                              float* __restrict__ featA) {
    bool bf = probe_bf16(scale);
    int p = blockIdx.x * 256 + threadIdx.x;
    if (p >= N1_) return;
    float fx = ldin(ffix, p, bf);
    featA[p] = (fx > 0.0f) ? fx : ldin(finit, p, bf);
}

// --------- kernel 3: 3x3 conv (8->24) + offsets/affinity epilogue -----------
// Offset pairing per reference: off[:, t, 0] = oa[2t] (y), off[:, t, 1] = oa[2t+1] (x)
__global__ __launch_bounds__(256) void k_conv(const void* __restrict__ guid,
                                              const void* __restrict__ conf,
                                              const void* __restrict__ scale,
                                              const float* __restrict__ wc,
                                              void* __restrict__ d_out,
                                              float* __restrict__ ws_off,
                                              float* __restrict__ ws_aff,
                                              int mode2) {
    bool bf = probe_bf16(scale);
    int p = blockIdx.x * 256 + threadIdx.x;
    if (p >= N1_) return;
    int b = p / HW_;
    int r = p - b * HW_;
    int h = r / W_;
    int w = r - h * W_;

    // load 8ch x 3x3 guidance neighborhood (zero-padded)
    float g[8][9];
    #pragma unroll
    for (int t = 0; t < 9; ++t) {
        int hh = h + t / 3 - 1;
        int ww = w + t % 3 - 1;
        bool v = (hh >= 0) && (hh < H_) && (ww >= 0) && (ww < W_);
        int idx0 = hh * W_ + ww;
        #pragma unroll
        for (int ci = 0; ci < 8; ++ci)
            g[ci][t] = v ? ldin(guid, (b * 8 + ci) * HW_ + idx0, bf) : 0.0f;
    }

    // 24 output channels, weights via uniform (scalar) loads
    float oa[24];
    #pragma unroll
    for (int co = 0; co < 24; ++co) {
        float a = wc[1728 + co];
        #pragma unroll
        for (int ci = 0; ci < 8; ++ci)
            #pragma unroll
            for (int t = 0; t < 9; ++t)
                a = fmaf(g[ci][t], wc[(co * 8 + ci) * 9 + t], a);
        oa[co] = a;
    }

    float scl = ldin(scale, 0, bf);
    float inv = 1.0f / (scl + 1e-8f);

    // affinity: tanh/scale, bilinear confidence at (h+oy, w+ox), normalize
    float aft[8];
    int cbase = b * HW_;
    #pragma unroll
    for (int t = 0; t < 8; ++t) {
        float a = tanhf(oa[16 + t]) * inv;
        float y = (float)h + oa[2 * t];        // y-offset = oa[2t]
        float x = (float)w + oa[2 * t + 1];    // x-offset = oa[2t+1]
        float y0f = floorf(y), x0f = floorf(x);
        int y0 = (int)y0f, x0 = (int)x0f;
        float wy = y - y0f, wx = x - x0f;
        int y0c = min(max(y0, 0), H_ - 1), y1c = min(max(y0 + 1, 0), H_ - 1);
        int x0c = min(max(x0, 0), W_ - 1), x1c = min(max(x0 + 1, 0), W_ - 1);
        bool vy0 = (y0 >= 0) && (y0 < H_), vy1 = (y0 >= -1) && (y0 < H_ - 1);
        bool vx0 = (x0 >= 0) && (x0 < W_), vx1 = (x0 >= -1) && (x0 < W_ - 1);
        float w00 = (1.0f - wy) * (1.0f - wx); w00 = (vy0 && vx0) ? w00 : 0.0f;
        float w01 = (1.0f - wy) * wx;          w01 = (vy0 && vx1) ? w01 : 0.0f;
        float w10 = wy * (1.0f - wx);          w10 = (vy1 && vx0) ? w10 : 0.0f;
        float w11 = wy * wx;                   w11 = (vy1 && vx1) ? w11 : 0.0f;
        float f00 = ldin(conf, cbase + y0c * W_ + x0c, bf);
        float f01 = ldin(conf, cbase + y0c * W_ + x1c, bf);
        float f10 = ldin(conf, cbase + y1c * W_ + x0c, bf);
        float f11 = ldin(conf, cbase + y1c * W_ + x1c, bf);
        float cv = w00 * f00 + w01 * f01 + w10 * f10 + w11 * f11;
        aft[t] = a * cv;
    }
    float s = 1e-4f;
    #pragma unroll
    for (int t = 0; t < 8; ++t) s += fabsf(aft[t]);
    s = fmaxf(s, 1.0f);
    float rs = 1.0f / s;
    float suma = 0.0f;
    #pragma unroll
    for (int t = 0; t < 8; ++t) { aft[t] *= rs; suma += aft[t]; }
    float aref = 1.0f - suma;

    // outputs: off (18 planes, center pair zero) and aff9 (9 planes)
    #pragma unroll
    for (int t = 0; t < 8; ++t) {
        int n9 = t + (t >= 4 ? 1 : 0);
        stout(d_out, N1_ + (b * 18 + 2 * n9)     * HW_ + r, bf, oa[2 * t]);
        stout(d_out, N1_ + (b * 18 + 2 * n9 + 1) * HW_ + r, bf, oa[2 * t + 1]);
        stout(d_out, 19 * N1_ + (b * 9 + n9) * HW_ + r, bf, aft[t]);
    }
    stout(d_out, N1_ + (b * 18 + 8) * HW_ + r, bf, 0.0f);
    stout(d_out, N1_ + (b * 18 + 9) * HW_ + r, bf, 0.0f);
    stout(d_out, 19 * N1_ + (b * 9 + 4) * HW_ + r, bf, aref);

    if (mode2) {
        #pragma unroll
        for (int t = 0; t < 8; ++t) {
            ws_off[t * N1_ + p]       = oa[2 * t];       // y
            ws_off[(8 + t) * N1_ + p] = oa[2 * t + 1];   // x
            int n9 = t + (t >= 4 ? 1 : 0);
            ws_aff[n9 * N1_ + p] = aft[t];
        }
        ws_aff[4 * N1_ + p] = aref;
    }
}

// ---------------- kernel 4: one propagation step ----------------------------
__global__ __launch_bounds__(256) void k_prop(const float* __restrict__ src,
                                              float* __restrict__ dst,
                                              const float* __restrict__ ws_off,
                                              const float* __restrict__ ws_aff,
                                              const void* __restrict__ d_out_all,
                                              const void* __restrict__ ffix_in,
                                              const void* __restrict__ scale,
                                              void* __restrict__ d_out_feat,
                                              int last, int mode2) {
    int p = blockIdx.x * 256 + threadIdx.x;
    if (p >= N1_) return;
    bool bf = probe_bf16(scale);
    int b = p / HW_;
    int r = p - b * HW_;
    int h = r / W_;
    int w = r - h * W_;
    const float* sp = src + b * HW_;

    float oy[8], ox[8], af[9];
    if (mode2) {
        #pragma unroll
        for (int t = 0; t < 8; ++t) {
            oy[t] = ws_off[t * N1_ + p];
            ox[t] = ws_off[(8 + t) * N1_ + p];
        }
        #pragma unroll
        for (int n = 0; n < 9; ++n) af[n] = ws_aff[n * N1_ + p];
    } else {
        #pragma unroll
        for (int t = 0; t < 8; ++t) {
            int n9 = t + (t >= 4 ? 1 : 0);
            oy[t] = ldin(d_out_all, N1_ + (b * 18 + 2 * n9)     * HW_ + r, bf);
            ox[t] = ldin(d_out_all, N1_ + (b * 18 + 2 * n9 + 1) * HW_ + r, bf);
        }
        #pragma unroll
        for (int n = 0; n < 9; ++n)
            af[n] = ldin(d_out_all, 19 * N1_ + (b * 9 + n) * HW_ + r, bf);
    }

    // center tap: zero offset -> exact grid sample
    float acc = af[4] * sp[r];

    #pragma unroll
    for (int t = 0; t < 8; ++t) {
        int n9 = t + (t >= 4 ? 1 : 0);
        float y = (float)(h + n9 / 3 - 1) + oy[t];
        float x = (float)(w + n9 % 3 - 1) + ox[t];
        float y0f = floorf(y), x0f = floorf(x);
        int y0 = (int)y0f, x0 = (int)x0f;
        float wy = y - y0f, wx = x - x0f;
        int y0c = min(max(y0, 0), H_ - 1), y1c = min(max(y0 + 1, 0), H_ - 1);
        int x0c = min(max(x0, 0), W_ - 1), x1c = min(max(x0 + 1, 0), W_ - 1);
        bool vy0 = (y0 >= 0) && (y0 < H_), vy1 = (y0 >= -1) && (y0 < H_ - 1);
        bool vx0 = (x0 >= 0) && (x0 < W_), vx1 = (x0 >= -1) && (x0 < W_ - 1);
        float w00 = (1.0f - wy) * (1.0f - wx); w00 = (vy0 && vx0) ? w00 : 0.0f;
        float w01 = (1.0f - wy) * wx;          w01 = (vy0 && vx1) ? w01 : 0.0f;
        float w10 = wy * (1.0f - wx);          w10 = (vy1 && vx0) ? w10 : 0.0f;
        float w11 = wy * wx;                   w11 = (vy1 && vx1) ? w11 : 0.0f;
        float f00 = sp[y0c * W_ + x0c];
        float f01 = sp[y0c * W_ + x1c];
        float f10 = sp[y1c * W_ + x0c];
        float f11 = sp[y1c * W_ + x1c];
        float v = w00 * f00 + w01 * f01 + w10 * f10 + w11 * f11;
        acc = fmaf(af[n9], v, acc);
    }

    if (last) {
        stout(d_out_feat, p, probe_bf16(scale), acc);
    } else {
        float fx = ldin(ffix_in, p, bf);
        dst[p] = (fx > 0.0f) ? fx : acc;   // fold next step's mask-replace
    }
}

extern "C" void kernel_launch(void* const* d_in, const int* in_sizes, int n_in,
                              void* d_out, int out_size, void* d_ws, size_t ws_size,
                              hipStream_t stream) {
    const void* feat_init  = d_in[0];
    const void* guidance   = d_in[1];
    const void* confidence = d_in[2];
    const void* feat_fix   = d_in[3];
    const void* w_oa       = d_in[4];
    const void* b_oa       = d_in[5];
    const void* scale      = d_in[6];

    float* wsf    = (float*)d_ws;
    float* featA  = wsf;
    float* featB  = wsf + N1_;
    float* wc     = wsf + 2 * (size_t)N1_;
    float* ws_off = wsf + 2 * (size_t)N1_ + 2048;
    float* ws_aff = ws_off + 16 * (size_t)N1_;

    size_t need2 = ((size_t)27 * N1_ + 2048) * sizeof(float);
    int mode2 = (ws_size >= need2) ? 1 : 0;

    int grid = (N1_ + 255) / 256;
    hipLaunchKernelGGL(k_prep_w, dim3(7), dim3(256), 0, stream, w_oa, b_oa, scale, wc);
    hipLaunchKernelGGL(k_init, dim3(grid), dim3(256), 0, stream,
                       feat_init, feat_fix, scale, featA);
    hipLaunchKernelGGL(k_conv, dim3(grid), dim3(256), 0, stream,
                       guidance, confidence, scale, wc, d_out, ws_off, ws_aff, mode2);

    float* a = featA;
    float* bbuf = featB;
    for (int it = 0; it < PT_; ++it) {
        int last = (it == PT_ - 1) ? 1 : 0;
        hipLaunchKernelGGL(k_prop, dim3(grid), dim3(256), 0, stream,
                           a, bbuf, ws_off, ws_aff, d_out, feat_fix, scale,
                           d_out, last, mode2);
        float* t = a; a = bbuf; bbuf = t;
    }
}